// Round 1
// 260.078 us; speedup vs baseline: 1.1415x; 1.1415x over previous
//
#include <hip/hip_runtime.h>
#include <hip/hip_bf16.h>

typedef __bf16 bf16_t;
typedef __bf16 bf16x8 __attribute__((ext_vector_type(8)));
typedef float floatx4 __attribute__((ext_vector_type(4)));
typedef unsigned int u32;

#define T_TOK 1024
#define DIM   1024
#define FF    512
#define NEXP  16

// ws layout
#define FLAG_OFF 0                 // int[6]
#define CNT_OFF  64                // int[16]
#define TOK_OFF  256               // int[16*1024], entry = token | (slot<<16)
#define H_OFF    65792             // bf16[3072][512] (row = t*3+slot)
#define XBF_OFF  (H_OFF + (size_t)3072*512*2)   // bf16[1024][1024] = 2 MB
#define WS_NEED  (XBF_OFF + (size_t)T_TOK*DIM*2)

__device__ inline float swiglu(float g, float u) {
    float a = fminf(fmaxf(-g, -60.f), 60.f);
    return g * u / (1.0f + __expf(a));
}

// async 16B global->LDS (linear dest: base + lane*16)
__device__ __forceinline__ void gload_lds16(const void* g, void* l) {
    __builtin_amdgcn_global_load_lds((const __attribute__((address_space(1))) u32*)g,
                                     (__attribute__((address_space(3))) u32*)l, 16, 0, 0);
}

__device__ __forceinline__ bf16x8 cvt8(float4 a, float4 b) {
    bf16x8 r;
    r[0]=(bf16_t)a.x; r[1]=(bf16_t)a.y; r[2]=(bf16_t)a.z; r[3]=(bf16_t)a.w;
    r[4]=(bf16_t)b.x; r[5]=(bf16_t)b.y; r[6]=(bf16_t)b.z; r[7]=(bf16_t)b.w;
    return r;
}

// compile-time-typed weight fragment: load raw now, convert at use
template<bool F32> struct Frag;
template<> struct Frag<true> {
    float4 a, b;
    __device__ __forceinline__ bf16x8 get() const { return cvt8(a, b); }
};
template<> struct Frag<false> {
    bf16x8 v;
    __device__ __forceinline__ bf16x8 get() const { return v; }
};
template<bool F32>
__device__ __forceinline__ Frag<F32> loadFrag(const void* base, size_t off) {
    Frag<F32> f;
    if constexpr (F32) {
        const float4* p = (const float4*)((const float*)base + off);
        f.a = p[0]; f.b = p[1];
    } else {
        f.v = *(const bf16x8*)((const bf16_t*)base + off);
    }
    return f;
}

// ---------------- per-input dtype detect (verified r4) ----------------
__global__ __launch_bounds__(64) void detect_kernel(
    const void* p0, const void* p1, const void* p2,
    const void* p3, const void* p4, const void* p5,
    int* __restrict__ flags)
{
    const void* ps[6] = {p0, p1, p2, p3, p4, p5};
    int j = blockIdx.x;
    int lane = threadIdx.x;
    const unsigned short* h = (const unsigned short*)ps[j];
    unsigned int bad = 0;
    for (int i = lane; i < 4096; i += 64) {
        unsigned int e = ((unsigned int)h[i] >> 7) & 0xFFu;
        if (e >= 0x90u) bad = 1;
    }
    unsigned long long b = __ballot(bad);
    if (lane == 0) flags[j] = (b != 0ull) ? 1 : 0;
}

// ---- runtime-typed loader (router + fallback only) ----
__device__ inline bf16x8 loadB8r(const void* base, size_t off, bool f32) {
    if (f32) {
        const float4* p = (const float4*)((const float*)base + off);
        float4 v0 = p[0], v1 = p[1];
        bf16x8 r;
        r[0]=(bf16_t)v0.x; r[1]=(bf16_t)v0.y; r[2]=(bf16_t)v0.z; r[3]=(bf16_t)v0.w;
        r[4]=(bf16_t)v1.x; r[5]=(bf16_t)v1.y; r[6]=(bf16_t)v1.z; r[7]=(bf16_t)v1.w;
        return r;
    } else {
        return *(const bf16x8*)((const bf16_t*)base + off);
    }
}

__device__ inline float bfbits(unsigned short u) {
    return __uint_as_float(((unsigned int)u) << 16);
}

// ---------------- Router: 256 blocks x 4 tokens; also emits x as bf16 ----------------
__global__ __launch_bounds__(256) void router_kernel(
    const void* __restrict__ x,
    const void* __restrict__ w_out,   // [8,1024]
    const void* __restrict__ w_in,    // [16,1024]
    float* __restrict__ selw_out,     // [T,3] fp32
    const int* __restrict__ flags,
    int* __restrict__ cnt, int* __restrict__ tok_enc,
    bf16_t* __restrict__ xb)          // optional bf16 copy of x
{
    const bool xf  = flags[0] != 0;
    const bool gof = flags[1] != 0;
    const bool gif = flags[2] != 0;
    const int tid = threadIdx.x;

    __shared__ __align__(16) float Gs[24 * 1024];   // 96 KB
    __shared__ float Ls[4][24];

    if (gof) {
        const float4* s = (const float4*)w_out; float4* d = (float4*)Gs;
        for (int i = tid; i < 2048; i += 256) d[i] = s[i];
    } else {
        const ushort4* s = (const ushort4*)w_out; float4* d = (float4*)Gs;
        for (int i = tid; i < 2048; i += 256) {
            ushort4 v = s[i];
            d[i] = make_float4(bfbits(v.x), bfbits(v.y), bfbits(v.z), bfbits(v.w));
        }
    }
    if (gif) {
        const float4* s = (const float4*)w_in; float4* d = (float4*)(Gs + 8 * 1024);
        for (int i = tid; i < 4096; i += 256) d[i] = s[i];
    } else {
        const ushort4* s = (const ushort4*)w_in; float4* d = (float4*)(Gs + 8 * 1024);
        for (int i = tid; i < 4096; i += 256) {
            ushort4 v = s[i];
            d[i] = make_float4(bfbits(v.x), bfbits(v.y), bfbits(v.z), bfbits(v.w));
        }
    }
    __syncthreads();

    const int wave = tid >> 6, lane = tid & 63;
    const int t = blockIdx.x * 4 + wave;

    float xv[16];
    if (xf) {
        const float* xp = (const float*)x + (size_t)t * DIM;
        #pragma unroll
        for (int i = 0; i < 16; i++) xv[i] = xp[lane + 64 * i];
    } else {
        const bf16_t* xp = (const bf16_t*)x + (size_t)t * DIM;
        #pragma unroll
        for (int i = 0; i < 16; i++) xv[i] = (float)xp[lane + 64 * i];
    }

    if (xb) {
        #pragma unroll
        for (int i = 0; i < 16; i++)
            xb[(size_t)t * DIM + lane + 64 * i] = (bf16_t)xv[i];
    }

    for (int j = 0; j < 24; j++) {
        const float* g = &Gs[j * 1024];
        float s = 0.f;
        #pragma unroll
        for (int i = 0; i < 16; i++) s += xv[i] * g[lane + 64 * i];
        #pragma unroll
        for (int m = 32; m >= 1; m >>= 1) s += __shfl_xor(s, m, 64);
        if (lane == 0) Ls[wave][j] = s;
    }

    if (lane == 0) {
        const float* logits = Ls[wave];
        float mx = logits[0];
        for (int o = 1; o < 8; o++) mx = fmaxf(mx, logits[o]);
        float p[8];
        for (int o = 0; o < 8; o++) p[o] = __expf(logits[o] - mx);
        int i0 = 0;
        for (int o = 1; o < 8; o++) if (logits[o] > logits[i0]) i0 = o;
        int i1 = (i0 == 0) ? 1 : 0;
        for (int o = 0; o < 8; o++) if (o != i0 && logits[o] > logits[i1]) i1 = o;
        float rsum = p[i0] + p[i1];
        float rw0 = p[i0] / rsum, rw1 = p[i1] / rsum;

        float a0 = logits[8 + i0 * 2], a1 = logits[8 + i0 * 2 + 1];
        int j00 = (a1 > a0) ? 1 : 0;
        float b0 = logits[8 + i1 * 2], b1 = logits[8 + i1 * 2 + 1];
        int j10 = (b1 > b0) ? 1 : 0;

        int   ids[3] = { i0 * 2 + j00, i0 * 2 + (1 - j00), i1 * 2 + j10 };
        float w[3]   = { rw0, rw0, rw1 };

        #pragma unroll
        for (int k = 0; k < 3; k++) {
            selw_out[t * 3 + k] = w[k];
            int e = ids[k];
            int pos = atomicAdd(&cnt[e], 1);
            if (pos >= 0 && pos < T_TOK)
                tok_enc[e * T_TOK + pos] = t | (k << 16);
        }
    }
}

// ---- gate+up+SwiGLU -> H : grid (e, mt=8 x 128tok, ft=8 x 64f) ----
// X staged via global_load_lds (XOR-swizzled src, linear dest); weights
// burst-loaded to registers one K-chunk ahead; one barrier per K-chunk.
template<bool GF, bool UF>
__device__ __forceinline__ void gateup_body(
    const bf16_t* __restrict__ xb,
    const void* __restrict__ wg, const void* __restrict__ wu,
    const int* __restrict__ cnt, const int* __restrict__ tok_enc,
    bf16_t* __restrict__ H,
    bf16_t (&Xs)[2][128][128], int* toks, int* hrow)
{
    const int e = blockIdx.x, mt = blockIdx.y, ft = blockIdx.z;
    int C = cnt[e]; if (C > T_TOK) C = T_TOK; if (C < 0) C = 0;
    if (mt * 128 >= C) return;

    const int tid = threadIdx.x;
    if (tid < 128) {
        int idx = mt * 128 + tid, t = 0, hr = -1;
        if (idx < C) {
            int enc = tok_enc[e * T_TOK + idx];
            int tt = enc & 0xFFFF, kk = (enc >> 16) & 0xFFFF;
            if (tt < T_TOK && kk < 3) { t = tt; hr = tt * 3 + kk; }
        }
        toks[tid] = t; hrow[tid] = hr;   // t=0 dummy: garbage stays in its own row
    }
    __syncthreads();

    const int wave = tid >> 6, lane = tid & 63;
    const int rsel = lane & 15, kq = lane >> 4;
    const int srow4 = lane >> 4, sg = lane & 15;
    const int f0 = ft * 64 + wave * 16;
    const size_t boff = (size_t)e * FF * DIM + (size_t)(f0 + rsel) * DIM + kq * 8;

    // per-lane pre-swizzled source pointers (8 rows of 4 per wave)
    const bf16_t* srcb[8];
    #pragma unroll
    for (int j = 0; j < 8; j++) {
        int r = wave * 32 + j * 4 + srow4;
        srcb[j] = xb + (size_t)toks[r] * DIM + ((sg ^ (r & 7)) << 3);
    }

    // stage K-chunk 0
    #pragma unroll
    for (int j = 0; j < 8; j++)
        gload_lds16(srcb[j], &Xs[0][wave * 32 + j * 4][0]);

    Frag<GF> fg[4]; Frag<UF> fu[4];
    #pragma unroll
    for (int i = 0; i < 4; i++) {
        fg[i] = loadFrag<GF>(wg, boff + i * 32);
        fu[i] = loadFrag<UF>(wu, boff + i * 32);
    }

    floatx4 ag[8], au[8];
    #pragma unroll
    for (int ms = 0; ms < 8; ms++) { ag[ms] = (floatx4){0,0,0,0}; au[ms] = (floatx4){0,0,0,0}; }

    __syncthreads();

    #pragma unroll
    for (int kb = 0; kb < 8; kb++) {
        Frag<GF> ng[4]; Frag<UF> nu[4];
        if (kb < 7) {
            #pragma unroll
            for (int j = 0; j < 8; j++)
                gload_lds16((const char*)srcb[j] + (kb + 1) * 256,
                            &Xs[(kb + 1) & 1][wave * 32 + j * 4][0]);
            #pragma unroll
            for (int i = 0; i < 4; i++) {
                ng[i] = loadFrag<GF>(wg, boff + (kb + 1) * 128 + i * 32);
                nu[i] = loadFrag<UF>(wu, boff + (kb + 1) * 128 + i * 32);
            }
        }
        const char* xbase = (const char*)&Xs[kb & 1][0][0];
        #pragma unroll
        for (int i = 0; i < 4; i++) {
            bf16x8 bg = fg[i].get(), bu = fu[i].get();
            #pragma unroll
            for (int ms = 0; ms < 8; ms++) {
                int row = ms * 16 + rsel;
                int g = (kq + i * 4) ^ (rsel & 7);      // read-side XOR swizzle
                bf16x8 a = *(const bf16x8*)(xbase + row * 256 + (g << 4));
                ag[ms] = __builtin_amdgcn_mfma_f32_16x16x32_bf16(a, bg, ag[ms], 0, 0, 0);
                au[ms] = __builtin_amdgcn_mfma_f32_16x16x32_bf16(a, bu, au[ms], 0, 0, 0);
            }
        }
        __syncthreads();
        if (kb < 7) {
            #pragma unroll
            for (int i = 0; i < 4; i++) { fg[i] = ng[i]; fu[i] = nu[i]; }
        }
    }

    #pragma unroll
    for (int ms = 0; ms < 8; ms++) {
        #pragma unroll
        for (int r = 0; r < 4; r++) {
            int m = ms * 16 + kq * 4 + r;
            int hr = hrow[m];
            if (hr >= 0)
                H[(size_t)hr * FF + f0 + rsel] = (bf16_t)swiglu(ag[ms][r], au[ms][r]);
        }
    }
}

__global__ __launch_bounds__(256, 1) void gateup_kernel(
    const bf16_t* __restrict__ xb,
    const void* __restrict__ wg, const void* __restrict__ wu,
    const int* __restrict__ flags, const int* __restrict__ cnt,
    const int* __restrict__ tok_enc, bf16_t* __restrict__ H)
{
    __shared__ __align__(16) bf16_t Xs[2][128][128];
    __shared__ int toks[128];
    __shared__ int hrow[128];
    const bool gf = flags[3] != 0, uf = flags[4] != 0;
    if (gf) {
        if (uf) gateup_body<true,  true >(xb, wg, wu, cnt, tok_enc, H, Xs, toks, hrow);
        else    gateup_body<true,  false>(xb, wg, wu, cnt, tok_enc, H, Xs, toks, hrow);
    } else {
        if (uf) gateup_body<false, true >(xb, wg, wu, cnt, tok_enc, H, Xs, toks, hrow);
        else    gateup_body<false, false>(xb, wg, wu, cnt, tok_enc, H, Xs, toks, hrow);
    }
}

// ---- down-proj + combine : grid (e, mt=16 x 64tok, dt=16 x 64d) ----
// H staged once via global_load_lds (swizzled); all 16 weight fragments
// burst-issued; zero barriers after the single staging sync.
template<bool DF>
__device__ __forceinline__ void down_body(
    const void* __restrict__ wd,
    const int* __restrict__ cnt, const int* __restrict__ tok_enc,
    const float* __restrict__ selw, const bf16_t* __restrict__ H,
    float* __restrict__ outp,
    bf16_t (&Hs)[64][512], int* toks, int* hrs, float* wts)
{
    const int e = blockIdx.x, mt = blockIdx.y, dt = blockIdx.z;
    int C = cnt[e]; if (C > T_TOK) C = T_TOK; if (C < 0) C = 0;
    if (mt * 64 >= C) return;

    const int tid = threadIdx.x;
    if (tid < 64) {
        int idx = mt * 64 + tid, t = -1, hr = 0; float w = 0.f;
        if (idx < C) {
            int enc = tok_enc[e * T_TOK + idx];
            int tt = enc & 0xFFFF, kk = (enc >> 16) & 0xFFFF;
            if (tt < T_TOK && kk < 3) { t = tt; hr = tt * 3 + kk; w = selw[tt * 3 + kk]; }
        }
        toks[tid] = t; hrs[tid] = hr; wts[tid] = w;
    }
    __syncthreads();

    const int wave = tid >> 6, lane = tid & 63;
    const int rsel = lane & 15, kq = lane >> 4;

    #pragma unroll
    for (int j = 0; j < 16; j++) {
        int r = wave * 16 + j;
        const bf16_t* src = H + (size_t)hrs[r] * FF + ((lane ^ (j & 7)) << 3);
        gload_lds16(src, &Hs[r][0]);
    }

    const int d0 = dt * 64 + wave * 16;
    const size_t boff = (size_t)e * DIM * FF + (size_t)(d0 + rsel) * FF + kq * 8;
    Frag<DF> fd[16];
    #pragma unroll
    for (int i = 0; i < 16; i++) fd[i] = loadFrag<DF>(wd, boff + i * 32);

    __syncthreads();

    floatx4 acc[4];
    #pragma unroll
    for (int ms = 0; ms < 4; ms++) acc[ms] = (floatx4){0,0,0,0};

    const char* hbase = (const char*)&Hs[0][0];
    #pragma unroll
    for (int i = 0; i < 16; i++) {
        bf16x8 b = fd[i].get();
        #pragma unroll
        for (int ms = 0; ms < 4; ms++) {
            int row = ms * 16 + rsel;
            int g = (kq + i * 4) ^ (rsel & 7);
            bf16x8 a = *(const bf16x8*)(hbase + row * 1024 + (g << 4));
            acc[ms] = __builtin_amdgcn_mfma_f32_16x16x32_bf16(a, b, acc[ms], 0, 0, 0);
        }
    }

    #pragma unroll
    for (int ms = 0; ms < 4; ms++) {
        #pragma unroll
        for (int r = 0; r < 4; r++) {
            int m = ms * 16 + kq * 4 + r, t = toks[m];
            if (t >= 0)
                atomicAdd(outp + (size_t)t * DIM + d0 + rsel, acc[ms][r] * wts[m]);
        }
    }
}

__global__ __launch_bounds__(256, 2) void down_kernel(
    const void* __restrict__ wd,
    const int* __restrict__ flags, const int* __restrict__ cnt,
    const int* __restrict__ tok_enc,
    const float* __restrict__ selw, const bf16_t* __restrict__ H,
    float* __restrict__ outp)
{
    __shared__ __align__(16) bf16_t Hs[64][512];
    __shared__ int toks[64];
    __shared__ int hrs[64];
    __shared__ float wts[64];
    const bool df = flags[5] != 0;
    if (df) down_body<true >(wd, cnt, tok_enc, selw, H, outp, Hs, toks, hrs, wts);
    else    down_body<false>(wd, cnt, tok_enc, selw, H, outp, Hs, toks, hrs, wts);
}

// ---------------- fallback fused FFN (verified r4) ----------------
__global__ __launch_bounds__(256) void ffn_kernel(
    const void* __restrict__ x,
    const void* __restrict__ wg, const void* __restrict__ wu, const void* __restrict__ wd,
    const int* __restrict__ flags, const int* __restrict__ cnt, const int* __restrict__ tok_enc,
    const float* __restrict__ selw, float* __restrict__ outp)
{
    const int e = blockIdx.x, tile = blockIdx.y;
    int C = cnt[e]; if (C > T_TOK) C = T_TOK; if (C < 0) C = 0;
    if (tile * 16 >= C) return;
    const bool xf = flags[0] != 0, gf = flags[3] != 0, uf = flags[4] != 0, df = flags[5] != 0;

    __shared__ __align__(16) bf16_t Xs[16][1032];
    __shared__ __align__(16) bf16_t Hs[16][520];
    __shared__ int toks[16];
    __shared__ float wts[16];
    const int tid = threadIdx.x;
    if (tid < 16) {
        int idx = tile * 16 + tid, t = -1; float w = 0.f;
        if (idx < C) {
            int enc = tok_enc[e * T_TOK + idx];
            int tt = enc & 0xFFFF, kk = (enc >> 16) & 0xFFFF;
            if (tt < T_TOK && kk < 3) { t = tt; w = selw[tt * 3 + kk]; }
        }
        toks[tid] = t; wts[tid] = w;
    }
    __syncthreads();
    {
        int row = tid >> 4, chunk = tid & 15;
        int t = toks[row];
        bf16x8* dst = (bf16x8*)&Xs[row][chunk * 64];
        if (t >= 0) {
            #pragma unroll
            for (int i = 0; i < 8; i++)
                dst[i] = loadB8r(x, (size_t)t * DIM + chunk * 64 + i * 8, xf);
        } else {
            bf16x8 z;
            #pragma unroll
            for (int kz = 0; kz < 8; kz++) z[kz] = (bf16_t)0.0f;
            #pragma unroll
            for (int i = 0; i < 8; i++) dst[i] = z;
        }
    }
    __syncthreads();

    const int wave = tid >> 6, lane = tid & 63;
    const int rsel = lane & 15, kq = lane >> 4;
    const size_t eoffF = (size_t)e * FF * DIM;
    for (int nt = 0; nt < 8; nt++) {
        const int f0 = wave * 128 + nt * 16;
        const size_t boff = eoffF + (size_t)(f0 + rsel) * DIM + kq * 8;
        const bf16_t* ap = &Xs[rsel][kq * 8];
        floatx4 accg = {0.f,0.f,0.f,0.f};
        floatx4 accu = {0.f,0.f,0.f,0.f};
        for (int k0 = 0; k0 < DIM; k0 += 32) {
            bf16x8 a  = *(const bf16x8*)(ap + k0);
            bf16x8 bg = loadB8r(wg, boff + k0, gf);
            bf16x8 bu = loadB8r(wu, boff + k0, uf);
            accg = __builtin_amdgcn_mfma_f32_16x16x32_bf16(a, bg, accg, 0, 0, 0);
            accu = __builtin_amdgcn_mfma_f32_16x16x32_bf16(a, bu, accu, 0, 0, 0);
        }
        #pragma unroll
        for (int r = 0; r < 4; r++)
            Hs[kq * 4 + r][f0 + rsel] = (bf16_t)swiglu(accg[r], accu[r]);
    }
    __syncthreads();
    const size_t eoffD = (size_t)e * DIM * FF;
    for (int nt = 0; nt < 16; nt++) {
        const int d0 = wave * 256 + nt * 16;
        const size_t boff = eoffD + (size_t)(d0 + rsel) * FF + kq * 8;
        const bf16_t* ap = &Hs[rsel][kq * 8];
        floatx4 acc = {0.f,0.f,0.f,0.f};
        for (int k0 = 0; k0 < FF; k0 += 32) {
            bf16x8 a = *(const bf16x8*)(ap + k0);
            bf16x8 b = loadB8r(wd, boff + k0, df);
            acc = __builtin_amdgcn_mfma_f32_16x16x32_bf16(a, b, acc, 0, 0, 0);
        }
        #pragma unroll
        for (int r = 0; r < 4; r++) {
            int m = kq * 4 + r, t = toks[m];
            if (t >= 0) atomicAdd(outp + (size_t)t * DIM + d0 + rsel, acc[r] * wts[m]);
        }
    }
}

extern "C" void kernel_launch(void* const* d_in, const int* in_sizes, int n_in,
                              void* d_out, int out_size, void* d_ws, size_t ws_size,
                              hipStream_t stream)
{
    const void* x     = d_in[0];
    const void* w_out = d_in[1];
    const void* w_in  = d_in[2];
    const void* wg    = d_in[3];
    const void* wu    = d_in[4];
    const void* wd    = d_in[5];
    float* out  = (float*)d_out;
    float* selw = out + (size_t)T_TOK * DIM;

    char* ws = (char*)d_ws;
    int*    flags = (int*)(ws + FLAG_OFF);
    int*    cnt   = (int*)(ws + CNT_OFF);
    int*    tok   = (int*)(ws + TOK_OFF);
    bf16_t* H     = (bf16_t*)(ws + H_OFF);
    bf16_t* xbf   = (bf16_t*)(ws + XBF_OFF);

    const bool full = ws_size >= (size_t)WS_NEED;

    hipMemsetAsync(cnt, 0, NEXP * sizeof(int), stream);
    hipMemsetAsync(out, 0, (size_t)T_TOK * DIM * sizeof(float), stream);

    detect_kernel<<<dim3(6), dim3(64), 0, stream>>>(x, w_out, w_in, wg, wu, wd, flags);

    router_kernel<<<dim3(T_TOK / 4), dim3(256), 0, stream>>>(
        x, w_out, w_in, selw, flags, cnt, tok, full ? xbf : (bf16_t*)nullptr);

    if (full) {
        gateup_kernel<<<dim3(NEXP, 8, 8), dim3(256), 0, stream>>>(
            xbf, wg, wu, flags, cnt, tok, H);
        down_kernel<<<dim3(NEXP, 16, 16), dim3(256), 0, stream>>>(
            wd, flags, cnt, tok, selw, H, out);
    } else {
        ffn_kernel<<<dim3(NEXP, 64), dim3(256), 0, stream>>>(
            x, wg, wu, wd, flags, cnt, tok, selw, out);
    }
}